// Round 4
// baseline (3418.771 us; speedup 1.0000x reference)
//
#include <hip/hip_runtime.h>

#define T_STEPS 512
#define BATCH   64
#define IN      512
#define HID     1024
#define GDIM    4096

typedef __attribute__((ext_vector_type(8))) short bf16x8_t;
typedef __attribute__((ext_vector_type(4))) float f32x4_t;

__device__ __forceinline__ unsigned short f2bf(float f) {
  union { float f; unsigned int u; } v; v.f = f;
  unsigned int r = v.u + 0x7FFFu + ((v.u >> 16) & 1u);
  return (unsigned short)(r >> 16);
}
__device__ __forceinline__ float bf2f(unsigned short u) {
  union { unsigned int u; float f; } v; v.u = ((unsigned int)u) << 16;
  return v.f;
}
__device__ __forceinline__ float sigmoidf_(float x) {
  return 1.0f / (1.0f + __expf(-x));
}
__device__ __forceinline__ float tanhf_(float x) {
  return 1.0f - 2.0f / (__expf(2.0f * x) + 1.0f);
}

// ---------------- fp32 -> bf16 conversion ----------------
__global__ void k_cvt(const float* __restrict__ src, unsigned short* __restrict__ dst, int n) {
  int i = (blockIdx.x * blockDim.x + threadIdx.x) * 4;
  if (i + 3 < n) {
    float4 f = *(const float4*)(src + i);
    ushort4 o;
    o.x = f2bf(f.x); o.y = f2bf(f.y); o.z = f2bf(f.z); o.w = f2bf(f.w);
    *(ushort4*)(dst + i) = o;
  }
}

__global__ void k_bias(const float* __restrict__ a, const float* __restrict__ b,
                       float* __restrict__ o) {
  int i = blockIdx.x * blockDim.x + threadIdx.x;
  if (i < GDIM) o[i] = a[i] + b[i];
}

// ---------------- persistent fused LSTM (cooperative) ----------------
// 128 blocks x 512 threads. blockIdx = bg*32 + cso. Block owns batches
// [bg*16,+16) x hidden cols [cso*32,+32). 8 waves: gate g = w&3, col-half
// ch = w>>2. W_hh slice in VGPRs (128/wave) for all 512 steps; x-projection
// for step t+1 computed in the slack window after posting h(t) (x prefetched
// to regs before the poll; W_ih streamed from L2). Cross-block h exchange:
// relaxed-agent sc0/sc1 accesses only; per-producer monotonic store-flags.
__global__ __launch_bounds__(512, 1) void k_lstm_persist(
    const float* __restrict__ x,
    const unsigned short* __restrict__ Wih,
    const unsigned short* __restrict__ Whh,
    const float* __restrict__ bih,
    const float* __restrict__ bhh,
    unsigned short* __restrict__ hbuf0,
    unsigned short* __restrict__ hbuf1,
    float* __restrict__ out,
    float* __restrict__ hT,
    float* __restrict__ cT,
    unsigned int* __restrict__ flags)
{
  __shared__ __align__(16) unsigned short Hlds[16 * 1024];  // 32KB, XOR-swizzled (2048B rows)
  __shared__ __align__(16) unsigned short Xlds[16 * 512];   // 16KB, XOR-swizzled (1024B rows)
  __shared__ float Glds[4][16][34];
  __shared__ float XGlds[4][16][34];

  const int tid = threadIdx.x;
  const int w = tid >> 6, l = tid & 63;
  const int bg  = blockIdx.x >> 5;      // batch group 0..3
  const int cso = blockIdx.x & 31;      // hidden-col slice 0..31 (32 cols each)
  const int b0 = bg * 16, n0 = cso * 32;
  const int g = w & 3, ch = w >> 2;
  const int gc = (g << 10) + n0 + ch * 16 + (l & 15);   // gate column in [0,4096)

  // W_hh fragments: 32 x bf16x8 = 128 VGPRs, resident for the whole kernel
  const unsigned short* wp = Whh + (size_t)gc * HID + ((l >> 4) * 8);
  bf16x8_t wfrag[32];
  #pragma unroll
  for (int ks = 0; ks < 32; ++ks)
    wfrag[ks] = *(const bf16x8_t*)(wp + ks * 32);
  const unsigned short* wpx = Wih + (size_t)gc * IN + ((l >> 4) * 8);

  const float bv = bih[gc] + bhh[gc];

  // elementwise ids (512 threads <-> 16 batches x 32 cols)
  const int eb = tid >> 5, en = tid & 31;
  const size_t ci = (size_t)(b0 + eb) * HID + n0 + en;
  float creg = 0.0f;

  // swizzled LDS addressing for MFMA A-fragments
  const int abase = (l & 15) * 2048 + ((l >> 4) * 16);
  const int xbase = (l & 15) * 1024 + ((l >> 4) * 16);
  const int amask = (l & 7) << 4;

  unsigned int* const fgrp = flags + bg * 64;
  unsigned int* const fown = fgrp + cso;
  const unsigned int* const fpoll = fgrp + (l & 31);

  const int mrow = (l >> 4) * 4, mcc = ch * 16 + (l & 15);

  // ---- prologue: compute xp(0) into XGlds ----
  {
    const float4* x4 = (const float4*)(x + (size_t)b0 * IN);
    float4 a0 = x4[2 * tid],          a1 = x4[2 * tid + 1];
    float4 b0v = x4[2 * (512 + tid)], b1v = x4[2 * (512 + tid) + 1];
    union { bf16x8_t v; unsigned short s[8]; } u;
    u.s[0]=f2bf(a0.x); u.s[1]=f2bf(a0.y); u.s[2]=f2bf(a0.z); u.s[3]=f2bf(a0.w);
    u.s[4]=f2bf(a1.x); u.s[5]=f2bf(a1.y); u.s[6]=f2bf(a1.z); u.s[7]=f2bf(a1.w);
    { int d = tid * 16; int sd = d ^ (((d >> 10) & 7) << 4);
      *(bf16x8_t*)((char*)Xlds + sd) = u.v; }
    u.s[0]=f2bf(b0v.x); u.s[1]=f2bf(b0v.y); u.s[2]=f2bf(b0v.z); u.s[3]=f2bf(b0v.w);
    u.s[4]=f2bf(b1v.x); u.s[5]=f2bf(b1v.y); u.s[6]=f2bf(b1v.z); u.s[7]=f2bf(b1v.w);
    { int d = (512 + tid) * 16; int sd = d ^ (((d >> 10) & 7) << 4);
      *(bf16x8_t*)((char*)Xlds + sd) = u.v; }
    __syncthreads();
    f32x4_t sx = {0,0,0,0};
    #pragma unroll
    for (int ks = 0; ks < 16; ++ks) {
      bf16x8_t a = *(const bf16x8_t*)((const char*)Xlds + ((xbase + ks*64) ^ amask));
      bf16x8_t b = *(const bf16x8_t*)(wpx + ks * 32);
      sx = __builtin_amdgcn_mfma_f32_16x16x32_bf16(a, b, sx, 0, 0, 0);
    }
    XGlds[g][mrow + 0][mcc] = sx[0] + bv;
    XGlds[g][mrow + 1][mcc] = sx[1] + bv;
    XGlds[g][mrow + 2][mcc] = sx[2] + bv;
    XGlds[g][mrow + 3][mcc] = sx[3] + bv;
  }

  #pragma unroll 1
  for (int t = 0; t < T_STEPS; ++t) {
    const unsigned short* hc = (t & 1) ? hbuf1 : hbuf0;
    unsigned short*       hn = (t & 1) ? hbuf0 : hbuf1;

    // prefetch x(t+1) into regs (plain cached loads) BEFORE the poll
    float4 xa0, xa1, xb0, xb1;
    if (t + 1 < T_STEPS) {
      const float4* x4 = (const float4*)(x + ((size_t)(t + 1) * BATCH + b0) * IN);
      xa0 = x4[2 * tid];          xa1 = x4[2 * tid + 1];
      xb0 = x4[2 * (512 + tid)];  xb1 = x4[2 * (512 + tid) + 1];
      asm volatile("" ::: "memory");
    }

    // wait for all 32 producers of h(t-1) in this batch group
    if (t > 0) {
      for (;;) {
        unsigned int v = __hip_atomic_load(fpoll, __ATOMIC_RELAXED,
                                           __HIP_MEMORY_SCOPE_AGENT);
        if (__all((int)(v >= (unsigned int)t))) break;
        __builtin_amdgcn_s_sleep(1);
      }
    }

    // stage h[bg] slice (16 x 1024 bf16 = 32KB) with per-access cache bypass
    {
      const char* hsrc = (const char*)(hc + (size_t)b0 * HID);
      bf16x8_t hv4[4];
      #pragma unroll
      for (int i = 0; i < 4; ++i) {
        unsigned long long ap_ = (unsigned long long)(hsrc + (size_t)(i * 512 + tid) * 16);
        asm volatile("global_load_dwordx4 %0, %1, off sc0 sc1"
                     : "=v"(hv4[i]) : "v"(ap_) : "memory");
      }
      asm volatile("s_waitcnt vmcnt(0)" ::: "memory");
      __builtin_amdgcn_sched_barrier(0);
      #pragma unroll
      for (int i = 0; i < 4; ++i) {
        int d = (i * 512 + tid) * 16;
        int sd = d ^ (((d >> 11) & 7) << 4);
        *(bf16x8_t*)((char*)Hlds + sd) = hv4[i];
      }
    }
    __syncthreads();

    // h @ W_hh^T for this wave's 16 gate-cols
    f32x4_t ac0 = {0,0,0,0}, ac1 = {0,0,0,0}, ac2 = {0,0,0,0}, ac3 = {0,0,0,0};
    #pragma unroll
    for (int ks = 0; ks < 32; ks += 4) {
      bf16x8_t a0 = *(const bf16x8_t*)((const char*)Hlds + ((abase + (ks+0)*64) ^ amask));
      bf16x8_t a1 = *(const bf16x8_t*)((const char*)Hlds + ((abase + (ks+1)*64) ^ amask));
      bf16x8_t a2 = *(const bf16x8_t*)((const char*)Hlds + ((abase + (ks+2)*64) ^ amask));
      bf16x8_t a3 = *(const bf16x8_t*)((const char*)Hlds + ((abase + (ks+3)*64) ^ amask));
      ac0 = __builtin_amdgcn_mfma_f32_16x16x32_bf16(a0, wfrag[ks+0], ac0, 0, 0, 0);
      ac1 = __builtin_amdgcn_mfma_f32_16x16x32_bf16(a1, wfrag[ks+1], ac1, 0, 0, 0);
      ac2 = __builtin_amdgcn_mfma_f32_16x16x32_bf16(a2, wfrag[ks+2], ac2, 0, 0, 0);
      ac3 = __builtin_amdgcn_mfma_f32_16x16x32_bf16(a3, wfrag[ks+3], ac3, 0, 0, 0);
    }
    f32x4_t s = ac0 + ac1 + ac2 + ac3;
    Glds[g][mrow + 0][mcc] = s[0];
    Glds[g][mrow + 1][mcc] = s[1];
    Glds[g][mrow + 2][mcc] = s[2];
    Glds[g][mrow + 3][mcc] = s[3];
    __syncthreads();

    // elementwise epilogue
    float pre0 = Glds[0][eb][en] + XGlds[0][eb][en];
    float pre1 = Glds[1][eb][en] + XGlds[1][eb][en];
    float pre2 = Glds[2][eb][en] + XGlds[2][eb][en];
    float pre3 = Glds[3][eb][en] + XGlds[3][eb][en];
    float ig = sigmoidf_(pre0);
    float fg = sigmoidf_(pre1);
    float gg = tanhf_(pre2);
    float og = sigmoidf_(pre3);
    creg = fg * creg + ig * gg;
    float hv = og * tanhf_(creg);

    out[((size_t)t * BATCH + b0 + eb) * HID + n0 + en] = hv;

    if (t == T_STEPS - 1) {
      hT[ci] = hv;
      cT[ci] = creg;
    } else {
      // publish h(t): packed bf16 pairs, relaxed-agent stores (no cache maint.)
      unsigned short mybf = f2bf(hv);
      unsigned short pbf = (unsigned short)(unsigned int)
          __shfl_xor((int)(unsigned int)mybf, 1, 64);
      if ((l & 1) == 0) {
        unsigned int pk = ((unsigned int)mybf) | (((unsigned int)pbf) << 16);
        __hip_atomic_store((unsigned int*)(hn + ci), pk,
                           __ATOMIC_RELAXED, __HIP_MEMORY_SCOPE_AGENT);
      }
      asm volatile("s_waitcnt vmcnt(0)" ::: "memory");  // own stores performed
      __syncthreads();                                   // all waves drained
      if (tid == 0)
        __hip_atomic_store(fown, (unsigned int)(t + 1),
                           __ATOMIC_RELAXED, __HIP_MEMORY_SCOPE_AGENT);

      // ---- slack window: compute xp(t+1) into XGlds ----
      union { bf16x8_t v; unsigned short s[8]; } u;
      u.s[0]=f2bf(xa0.x); u.s[1]=f2bf(xa0.y); u.s[2]=f2bf(xa0.z); u.s[3]=f2bf(xa0.w);
      u.s[4]=f2bf(xa1.x); u.s[5]=f2bf(xa1.y); u.s[6]=f2bf(xa1.z); u.s[7]=f2bf(xa1.w);
      { int d = tid * 16; int sd = d ^ (((d >> 10) & 7) << 4);
        *(bf16x8_t*)((char*)Xlds + sd) = u.v; }
      u.s[0]=f2bf(xb0.x); u.s[1]=f2bf(xb0.y); u.s[2]=f2bf(xb0.z); u.s[3]=f2bf(xb0.w);
      u.s[4]=f2bf(xb1.x); u.s[5]=f2bf(xb1.y); u.s[6]=f2bf(xb1.z); u.s[7]=f2bf(xb1.w);
      { int d = (512 + tid) * 16; int sd = d ^ (((d >> 10) & 7) << 4);
        *(bf16x8_t*)((char*)Xlds + sd) = u.v; }
      __syncthreads();
      f32x4_t sx = {0,0,0,0};
      #pragma unroll
      for (int ks = 0; ks < 16; ++ks) {
        bf16x8_t a = *(const bf16x8_t*)((const char*)Xlds + ((xbase + ks*64) ^ amask));
        bf16x8_t b = *(const bf16x8_t*)(wpx + ks * 32);
        sx = __builtin_amdgcn_mfma_f32_16x16x32_bf16(a, b, sx, 0, 0, 0);
      }
      XGlds[g][mrow + 0][mcc] = sx[0] + bv;
      XGlds[g][mrow + 1][mcc] = sx[1] + bv;
      XGlds[g][mrow + 2][mcc] = sx[2] + bv;
      XGlds[g][mrow + 3][mcc] = sx[3] + bv;
      // next iteration's stage-h __syncthreads orders these writes before reads
    }
  }
}

// ---------------- fallback per-timestep kernel (small workspace) ----------------
__global__ __launch_bounds__(256) void k_step_fused(
    const unsigned short* __restrict__ hprev,
    unsigned short* __restrict__ hnext,
    float* __restrict__ cstate,
    const unsigned short* __restrict__ Whh,
    const unsigned short* __restrict__ Wih,
    const float* __restrict__ x,
    const float* __restrict__ bias,
    float* __restrict__ out,
    float* __restrict__ hT, float* __restrict__ cT,
    int t, int is_last)
{
  const int RS = 1560;
  const int XB = 1032;
  __shared__ unsigned short Hlds[16 * RS];
  __shared__ float Glds[4][16][17];
  const int tid = threadIdx.x;
  const int w = tid >> 6, l = tid & 63;
  const int bg = blockIdx.x >> 6, hs = blockIdx.x & 63;
  const int b0 = bg * 16, n0 = hs * 16;

  #pragma unroll
  for (int it = 0; it < 8; ++it) {
    int chunk = tid + it * 256;
    int row = chunk >> 7;
    int cc  = (chunk & 127) * 8;
    *(bf16x8_t*)&Hlds[row * RS + cc] =
        *(const bf16x8_t*)(hprev + (size_t)(b0 + row) * HID + cc);
  }
  #pragma unroll
  for (int it = 0; it < 4; ++it) {
    int chunk = tid + it * 256;
    int row = chunk >> 6;
    int cc  = (chunk & 63) * 8;
    const float* src = x + ((size_t)t * BATCH + b0 + row) * IN + cc;
    float4 f0 = *(const float4*)(src);
    float4 f1 = *(const float4*)(src + 4);
    union { bf16x8_t v; unsigned short s[8]; } u;
    u.s[0]=f2bf(f0.x); u.s[1]=f2bf(f0.y); u.s[2]=f2bf(f0.z); u.s[3]=f2bf(f0.w);
    u.s[4]=f2bf(f1.x); u.s[5]=f2bf(f1.y); u.s[6]=f2bf(f1.z); u.s[7]=f2bf(f1.w);
    *(bf16x8_t*)&Hlds[row * RS + XB + cc] = u.v;
  }
  __syncthreads();

  f32x4_t acc = {0.f, 0.f, 0.f, 0.f};
  const int gcol = (w << 10) + n0 + (l & 15);
  const unsigned short* wp = Whh + (size_t)gcol * HID + ((l >> 4) * 8);
  const unsigned short* ap = &Hlds[(l & 15) * RS + ((l >> 4) * 8)];
  #pragma unroll 4
  for (int ks = 0; ks < 32; ++ks) {
    bf16x8_t a = *(const bf16x8_t*)(ap);
    bf16x8_t b = *(const bf16x8_t*)(wp);
    acc = __builtin_amdgcn_mfma_f32_16x16x32_bf16(a, b, acc, 0, 0, 0);
    ap += 32; wp += 32;
  }
  const unsigned short* wpx = Wih + (size_t)gcol * IN + ((l >> 4) * 8);
  const unsigned short* apx = &Hlds[(l & 15) * RS + XB + ((l >> 4) * 8)];
  #pragma unroll 4
  for (int ks = 0; ks < 16; ++ks) {
    bf16x8_t a = *(const bf16x8_t*)(apx);
    bf16x8_t b = *(const bf16x8_t*)(wpx);
    acc = __builtin_amdgcn_mfma_f32_16x16x32_bf16(a, b, acc, 0, 0, 0);
    apx += 32; wpx += 32;
  }

  {
    int r0 = (l >> 4) * 4, cc = l & 15;
    Glds[w][r0 + 0][cc] = acc[0];
    Glds[w][r0 + 1][cc] = acc[1];
    Glds[w][r0 + 2][cc] = acc[2];
    Glds[w][r0 + 3][cc] = acc[3];
  }
  __syncthreads();

  int b = tid >> 4, n = tid & 15;
  float pre[4];
  #pragma unroll
  for (int g = 0; g < 4; ++g)
    pre[g] = Glds[g][b][n] + bias[(g << 10) + n0 + n];
  float ig = sigmoidf_(pre[0]);
  float fg = sigmoidf_(pre[1]);
  float gg = tanhf_(pre[2]);
  float og = sigmoidf_(pre[3]);
  size_t ci = (size_t)(b0 + b) * HID + n0 + n;
  float cn = fg * cstate[ci] + ig * gg;
  float hv = og * tanhf_(cn);
  cstate[ci] = cn;
  out[((size_t)t * BATCH + b0 + b) * HID + n0 + n] = hv;
  hnext[ci] = f2bf(hv);
  if (is_last) { hT[ci] = hv; cT[ci] = cn; }
}

// ---------------- host launch ----------------
extern "C" void kernel_launch(void* const* d_in, const int* in_sizes, int n_in,
                              void* d_out, int out_size, void* d_ws, size_t ws_size,
                              hipStream_t stream) {
  const float* x    = (const float*)d_in[0];
  const float* Wihf = (const float*)d_in[1];
  const float* bih  = (const float*)d_in[2];
  const float* Whhf = (const float*)d_in[3];
  const float* bhh  = (const float*)d_in[4];
  float* out = (float*)d_out;

  char* ws = (char*)d_ws;
  size_t off = 0;
  auto take = [&](size_t bytes) {
    char* p = ws + off;
    off = (off + bytes + 255) & ~(size_t)255;
    return p;
  };
  unsigned short* wih_b = (unsigned short*)take((size_t)GDIM * IN * 2);   // 4 MB
  unsigned short* whh_b = (unsigned short*)take((size_t)GDIM * HID * 2);  // 8 MB
  float*          bias  = (float*)take((size_t)GDIM * 4);
  unsigned short* h0    = (unsigned short*)take((size_t)BATCH * HID * 2);
  unsigned short* h1    = (unsigned short*)take((size_t)BATCH * HID * 2);
  float*          cbuf  = (float*)take((size_t)BATCH * HID * 4);
  unsigned int*   flags = (unsigned int*)take((size_t)4 * 64 * 4);
  size_t full_need = off;
  const int primary = (ws_size >= full_need) ? 1 : 0;
  (void)in_sizes; (void)n_in; (void)out_size;

  k_cvt<<<(GDIM * IN / 4 + 255) / 256, 256, 0, stream>>>(Wihf, wih_b, GDIM * IN);
  k_cvt<<<(GDIM * HID / 4 + 255) / 256, 256, 0, stream>>>(Whhf, whh_b, GDIM * HID);
  (void)hipMemsetAsync(h0, 0, (size_t)BATCH * HID * 2, stream);

  float* hT = out + (size_t)T_STEPS * BATCH * HID;
  float* cT = hT + (size_t)BATCH * HID;

  if (primary) {
    (void)hipMemsetAsync(flags, 0, (size_t)4 * 64 * 4, stream);
    void* p_x = (void*)x;       void* p_wih = (void*)wih_b;
    void* p_whh = (void*)whh_b; void* p_bih = (void*)bih;
    void* p_bhh = (void*)bhh;   void* p_h0 = (void*)h0;
    void* p_h1 = (void*)h1;     void* p_out = (void*)out;
    void* p_hT = (void*)hT;     void* p_cT = (void*)cT;
    void* p_fl = (void*)flags;
    void* args[11] = {&p_x, &p_wih, &p_whh, &p_bih, &p_bhh, &p_h0, &p_h1,
                      &p_out, &p_hT, &p_cT, &p_fl};
    (void)hipLaunchCooperativeKernel((const void*)k_lstm_persist,
                                     dim3(128), dim3(512), args, 0, stream);
  } else {
    k_bias<<<(GDIM + 255) / 256, 256, 0, stream>>>(bih, bhh, bias);
    (void)hipMemsetAsync(cbuf, 0, (size_t)BATCH * HID * 4, stream);
    unsigned short* hp = h0;
    unsigned short* hn = h1;
    for (int t = 0; t < T_STEPS; ++t) {
      int last = (t == T_STEPS - 1) ? 1 : 0;
      k_step_fused<<<256, 256, 0, stream>>>(hp, hn, cbuf, whh_b, wih_b, x, bias,
                                            out, hT, cT, t, last);
      unsigned short* tmp = hp; hp = hn; hn = tmp;
    }
  }
}